// Round 1
// baseline (85.735 us; speedup 1.0000x reference)
//
#include <hip/hip_runtime.h>

#define HWC 16384      // H*W
#define WD  128
#define HD  128
#define NC  64
#define EPSV 1e-6f

// ---------------- Kernel 1: head 1x1 conv + ReLU -> h (in d_ws) -------------
__global__ __launch_bounds__(256) void k_head(const float* __restrict__ x,
                                              const float* __restrict__ Wh,
                                              float* __restrict__ h) {
  __shared__ float xs[64 * 64];   // [c][w]
  __shared__ float ws[64 * 64];   // [o][c] as in memory
  int t = threadIdx.x;
  int bid = blockIdx.x;
  int seg = bid & 1;
  int y = (bid >> 1) & 127;
  int b = bid >> 8;
  int w0 = seg * 64;

#pragma unroll
  for (int i = 0; i < 16; ++i) ws[t + i * 256] = Wh[t + i * 256];

  int wl = t & 63;
  int cl = t >> 6;
  const float* xb = x + (size_t)b * NC * HWC + (size_t)y * WD + w0;
#pragma unroll
  for (int i = 0; i < 16; ++i) {
    int c = cl * 16 + i;
    xs[c * 64 + wl] = xb[(size_t)c * HWC + wl];
  }
  __syncthreads();

  float acc[16];
#pragma unroll
  for (int j = 0; j < 16; ++j) acc[j] = 0.f;

#pragma unroll 16
  for (int c = 0; c < 64; ++c) {
    float xv = xs[c * 64 + wl];
#pragma unroll
    for (int j = 0; j < 16; ++j)
      acc[j] += ws[(cl * 16 + j) * 64 + c] * xv;
  }

  float* hb = h + (size_t)b * NC * HWC + (size_t)y * WD + w0;
#pragma unroll
  for (int j = 0; j < 16; ++j) {
    float v = acc[j];
    hb[(size_t)(cl * 16 + j) * HWC + wl] = v > 0.f ? v : 0.f;
  }
}

// ---------------- Kernel 2: per-pixel rank-collapsed NMF -> UV (in d_out) ---
__global__ __launch_bounds__(256) void k_nmf(const float* __restrict__ h,
                                             float* __restrict__ uv) {
  int t = threadIdx.x;
  int p = blockIdx.x * 256 + t;
  int w = p & 127;
  int y = (p >> 7) & 127;
  int b = p >> 14;
  const float* hb = h + (size_t)b * NC * HWC;

  int y0 = y - 2 < 0 ? 0 : y - 2;
  int y2 = y + 2 > 127 ? 127 : y + 2;
  int x0 = w - 2 < 0 ? 0 : w - 2;
  int x2 = w + 2 > 127 ? 127 : w + 2;
  int off[9];
  off[0] = y0 * WD + x0; off[1] = y0 * WD + w; off[2] = y0 * WD + x2;
  off[3] = y  * WD + x0; off[4] = y  * WD + w; off[5] = y  * WD + x2;
  off[6] = y2 * WD + x0; off[7] = y2 * WD + w; off[8] = y2 * WD + x2;

  float sumk[9], A[9];
#pragma unroll
  for (int k = 0; k < 9; ++k) { sumk[k] = 0.f; A[k] = 0.f; }
  float S = 0.f;

  // Pass 1: mc (on the fly), nk sums, A, S
#pragma unroll 8
  for (int c = 0; c < 64; ++c) {
    const float* hc = hb + (size_t)c * HWC;
    float tap[9];
#pragma unroll
    for (int k = 0; k < 9; ++k) tap[k] = hc[off[k]];
    float m = 0.f;
#pragma unroll
    for (int k = 0; k < 9; ++k) m += tap[k];
    m *= (1.f / 9.f);
    S += m * m;
#pragma unroll
    for (int k = 0; k < 9; ++k) { sumk[k] += tap[k]; A[k] += m * tap[k]; }
  }

  float Vk[9];
#pragma unroll
  for (int k = 0; k < 9; ++k) {
    float nk = sumk[k] * (1.f / 64.f);
    Vk[k] = nk * (A[k] / (3.f * nk * S + EPSV));
  }
  float T = 0.f;
#pragma unroll
  for (int k = 0; k < 9; ++k) T += Vk[k] * Vk[k];
  float V4 = Vk[4];

  float* uvb = uv + (size_t)b * NC * HWC + (size_t)y * WD + w;

  // Pass 2: recompute mc, B, U, UV; write UV
#pragma unroll 8
  for (int c = 0; c < 64; ++c) {
    const float* hc = hb + (size_t)c * HWC;
    float tap[9];
#pragma unroll
    for (int k = 0; k < 9; ++k) tap[k] = hc[off[k]];
    float m = 0.f, Bc = 0.f;
#pragma unroll
    for (int k = 0; k < 9; ++k) { m += tap[k]; Bc += tap[k] * Vk[k]; }
    m *= (1.f / 9.f);
    float Uc = m * (Bc / (3.f * m * T + EPSV));
    uvb[(size_t)c * HWC] = 3.f * Uc * V4;
  }
}

// ---------------- Kernel 3: tail 1x1 conv + residual, in-place on d_out ----
__global__ __launch_bounds__(256) void k_tail(const float* __restrict__ x,
                                              const float* __restrict__ Wt,
                                              float* __restrict__ io) {
  __shared__ float uvs[64 * 64];  // [o][w]
  __shared__ float ws[64 * 64];   // [c2][o] as in memory
  int t = threadIdx.x;
  int bid = blockIdx.x;
  int seg = bid & 1;
  int y = (bid >> 1) & 127;
  int b = bid >> 8;
  int w0 = seg * 64;

#pragma unroll
  for (int i = 0; i < 16; ++i) ws[t + i * 256] = Wt[t + i * 256];

  int wl = t & 63;
  int cl = t >> 6;
  float* iob = io + (size_t)b * NC * HWC + (size_t)y * WD + w0;
#pragma unroll
  for (int i = 0; i < 16; ++i) {
    int c = cl * 16 + i;
    uvs[c * 64 + wl] = iob[(size_t)c * HWC + wl];
  }
  __syncthreads();

  float acc[16];
#pragma unroll
  for (int j = 0; j < 16; ++j) acc[j] = 0.f;

#pragma unroll 16
  for (int o = 0; o < 64; ++o) {
    float uvv = uvs[o * 64 + wl];
#pragma unroll
    for (int j = 0; j < 16; ++j)
      acc[j] += ws[(cl * 16 + j) * 64 + o] * uvv;
  }

  const float* xb = x + (size_t)b * NC * HWC + (size_t)y * WD + w0;
#pragma unroll
  for (int j = 0; j < 16; ++j) {
    int c2 = cl * 16 + j;
    iob[(size_t)c2 * HWC + wl] = acc[j] + xb[(size_t)c2 * HWC + wl];
  }
}

extern "C" void kernel_launch(void* const* d_in, const int* in_sizes, int n_in,
                              void* d_out, int out_size, void* d_ws, size_t ws_size,
                              hipStream_t stream) {
  const float* x  = (const float*)d_in[0];
  const float* Wh = (const float*)d_in[1];
  const float* Wt = (const float*)d_in[2];
  float* out = (float*)d_out;
  float* h   = (float*)d_ws;   // 4*64*128*128*4 = 16.78 MB scratch

  k_head<<<1024, 256, 0, stream>>>(x, Wh, h);
  k_nmf<<<256, 256, 0, stream>>>(h, out);
  k_tail<<<1024, 256, 0, stream>>>(x, Wt, out);
}

// Round 2
// 62.081 us; speedup vs baseline: 1.3810x; 1.3810x over previous
//
#include <hip/hip_runtime.h>

#define HWC 16384      // H*W
#define WD  128
#define HD  128
#define NC  64
#define EPSV 1e-6f

// ---------------- Kernel 1: head 1x1 conv + ReLU -> h (in d_ws) -------------
__global__ __launch_bounds__(256) void k_head(const float* __restrict__ x,
                                              const float* __restrict__ Wh,
                                              float* __restrict__ h) {
  __shared__ float xs[64 * 64];   // [c][w]
  __shared__ float ws[64 * 64];   // [o][c] as in memory
  int t = threadIdx.x;
  int bid = blockIdx.x;
  int seg = bid & 1;
  int y = (bid >> 1) & 127;
  int b = bid >> 8;
  int w0 = seg * 64;

#pragma unroll
  for (int i = 0; i < 16; ++i) ws[t + i * 256] = Wh[t + i * 256];

  int wl = t & 63;
  int cl = t >> 6;
  const float* xb = x + (size_t)b * NC * HWC + (size_t)y * WD + w0;
#pragma unroll
  for (int i = 0; i < 16; ++i) {
    int c = cl * 16 + i;
    xs[c * 64 + wl] = xb[(size_t)c * HWC + wl];
  }
  __syncthreads();

  float acc[16];
#pragma unroll
  for (int j = 0; j < 16; ++j) acc[j] = 0.f;

#pragma unroll 16
  for (int c = 0; c < 64; ++c) {
    float xv = xs[c * 64 + wl];
#pragma unroll
    for (int j = 0; j < 16; ++j)
      acc[j] += ws[(cl * 16 + j) * 64 + c] * xv;
  }

  float* hb = h + (size_t)b * NC * HWC + (size_t)y * WD + w0;
#pragma unroll
  for (int j = 0; j < 16; ++j) {
    float v = acc[j];
    hb[(size_t)(cl * 16 + j) * HWC + wl] = v > 0.f ? v : 0.f;
  }
}

// ---------------- Kernel 2: per-pixel rank-collapsed NMF -> UV (in d_out) ---
// Block: 512 threads = 8 waves. Block owns one 64-pixel row segment.
// Wave wv handles channels [8*wv, 8*wv+8). Cross-wave reduction via LDS.
__global__ __launch_bounds__(512) void k_nmf(const float* __restrict__ h,
                                             float* __restrict__ uv) {
  __shared__ float red[8 * 64 * 21];  // [wv][lane][19 partials, pad->21]
  int t = threadIdx.x;
  int lane = t & 63;
  int wv = t >> 6;
  int bid = blockIdx.x;
  int seg = bid & 1;
  int y = (bid >> 1) & 127;
  int b = bid >> 8;
  int w0 = seg * 64;

  const float* hb = h + (size_t)b * NC * HWC;
  int rowoff[3];
  rowoff[0] = (y >= 2 ? y - 2 : 0) * WD;
  rowoff[1] = y * WD;
  rowoff[2] = (y <= 125 ? y + 2 : 127) * WD;
  int aw = w0 - 2 + lane; if (aw < 0) aw = 0;        // clamped left-tap col
  int bw = w0 + 2 + lane; if (bw > 127) bw = 127;    // clamped right-tap col

  float S = 0.f, sumk[9], A[9];
#pragma unroll
  for (int k = 0; k < 9; ++k) { sumk[k] = 0.f; A[k] = 0.f; }

  int c0 = wv * 8;

  // ---- Pass 1: partial S, sumk, A over this wave's 8 channels ----
#pragma unroll 2
  for (int c = c0; c < c0 + 8; ++c) {
    const float* hc = hb + (size_t)c * HWC;
    float tap[9];
#pragma unroll
    for (int r = 0; r < 3; ++r) {
      float av = hc[rowoff[r] + aw];
      float bv = hc[rowoff[r] + bw];
      float t0a = __shfl(av, lane + 2);
      float t0b = __shfl(bv, lane - 2);
      float t0 = (lane < 62) ? t0a : t0b;
      tap[r * 3 + 0] = av;
      tap[r * 3 + 1] = t0;
      tap[r * 3 + 2] = bv;
    }
    float m = 0.f;
#pragma unroll
    for (int k = 0; k < 9; ++k) m += tap[k];
    m *= (1.f / 9.f);
    S += m * m;
#pragma unroll
    for (int k = 0; k < 9; ++k) { sumk[k] += tap[k]; A[k] += m * tap[k]; }
  }

  // ---- Cross-wave reduction through LDS ----
  {
    int rb = (wv * 64 + lane) * 21;
    red[rb + 0] = S;
#pragma unroll
    for (int k = 0; k < 9; ++k) red[rb + 1 + k] = sumk[k];
#pragma unroll
    for (int k = 0; k < 9; ++k) red[rb + 10 + k] = A[k];
  }
  __syncthreads();
  float Sf = 0.f, sumkf[9], Af[9];
#pragma unroll
  for (int k = 0; k < 9; ++k) { sumkf[k] = 0.f; Af[k] = 0.f; }
#pragma unroll
  for (int v = 0; v < 8; ++v) {
    int rb = (v * 64 + lane) * 21;
    Sf += red[rb + 0];
#pragma unroll
    for (int k = 0; k < 9; ++k) sumkf[k] += red[rb + 1 + k];
#pragma unroll
    for (int k = 0; k < 9; ++k) Af[k] += red[rb + 10 + k];
  }

  float Vk[9];
#pragma unroll
  for (int k = 0; k < 9; ++k) {
    float nk = sumkf[k] * (1.f / 64.f);
    Vk[k] = nk * (Af[k] / (3.f * nk * Sf + EPSV));
  }
  float T = 0.f;
#pragma unroll
  for (int k = 0; k < 9; ++k) T += Vk[k] * Vk[k];
  float V4 = Vk[4];

  // ---- Pass 2: recompute taps, B, U, write UV (coalesced) ----
  float* uvb = uv + (size_t)b * NC * HWC + (size_t)y * WD + w0 + lane;
#pragma unroll 2
  for (int c = c0; c < c0 + 8; ++c) {
    const float* hc = hb + (size_t)c * HWC;
    float tap[9];
#pragma unroll
    for (int r = 0; r < 3; ++r) {
      float av = hc[rowoff[r] + aw];
      float bv = hc[rowoff[r] + bw];
      float t0a = __shfl(av, lane + 2);
      float t0b = __shfl(bv, lane - 2);
      float t0 = (lane < 62) ? t0a : t0b;
      tap[r * 3 + 0] = av;
      tap[r * 3 + 1] = t0;
      tap[r * 3 + 2] = bv;
    }
    float m = 0.f, Bc = 0.f;
#pragma unroll
    for (int k = 0; k < 9; ++k) { m += tap[k]; Bc += tap[k] * Vk[k]; }
    m *= (1.f / 9.f);
    float Uc = m * (Bc / (3.f * m * T + EPSV));
    uvb[(size_t)c * HWC] = 3.f * Uc * V4;
  }
}

// ---------------- Kernel 3: tail 1x1 conv + residual, in-place on d_out ----
__global__ __launch_bounds__(256) void k_tail(const float* __restrict__ x,
                                              const float* __restrict__ Wt,
                                              float* __restrict__ io) {
  __shared__ float uvs[64 * 64];  // [o][w]
  __shared__ float ws[64 * 64];   // [c2][o] as in memory
  int t = threadIdx.x;
  int bid = blockIdx.x;
  int seg = bid & 1;
  int y = (bid >> 1) & 127;
  int b = bid >> 8;
  int w0 = seg * 64;

#pragma unroll
  for (int i = 0; i < 16; ++i) ws[t + i * 256] = Wt[t + i * 256];

  int wl = t & 63;
  int cl = t >> 6;
  float* iob = io + (size_t)b * NC * HWC + (size_t)y * WD + w0;
#pragma unroll
  for (int i = 0; i < 16; ++i) {
    int c = cl * 16 + i;
    uvs[c * 64 + wl] = iob[(size_t)c * HWC + wl];
  }
  __syncthreads();

  float acc[16];
#pragma unroll
  for (int j = 0; j < 16; ++j) acc[j] = 0.f;

#pragma unroll 16
  for (int o = 0; o < 64; ++o) {
    float uvv = uvs[o * 64 + wl];
#pragma unroll
    for (int j = 0; j < 16; ++j)
      acc[j] += ws[(cl * 16 + j) * 64 + o] * uvv;
  }

  const float* xb = x + (size_t)b * NC * HWC + (size_t)y * WD + w0;
#pragma unroll
  for (int j = 0; j < 16; ++j) {
    int c2 = cl * 16 + j;
    iob[(size_t)c2 * HWC + wl] = acc[j] + xb[(size_t)c2 * HWC + wl];
  }
}

extern "C" void kernel_launch(void* const* d_in, const int* in_sizes, int n_in,
                              void* d_out, int out_size, void* d_ws, size_t ws_size,
                              hipStream_t stream) {
  const float* x  = (const float*)d_in[0];
  const float* Wh = (const float*)d_in[1];
  const float* Wt = (const float*)d_in[2];
  float* out = (float*)d_out;
  float* h   = (float*)d_ws;   // 4*64*128*128*4 = 16.78 MB scratch

  k_head<<<1024, 256, 0, stream>>>(x, Wh, h);
  k_nmf<<<1024, 512, 0, stream>>>(h, out);
  k_tail<<<1024, 256, 0, stream>>>(x, Wt, out);
}